// Round 10
// baseline (361.517 us; speedup 1.0000x reference)
//
#include <hip/hip_runtime.h>
#include <hip/hip_bf16.h>

#define N_NODES 50000
#define N_EDGES 640000
#define N_REL   200
#define D       128
#define CAP     64              // bucket capacity; max degree ~35 (Poisson 12.8)
#define RANGES  8               // one target-range per XCD
#define NODES_PER_RANGE (N_NODES / RANGES)   // 6250
#define CHUNK_EDGES 2560
#define N_CHUNKS (N_EDGES / CHUNK_EDGES)     // 250

typedef __attribute__((ext_vector_type(8))) short short8;   // 8 bf16 (4 VGPRs)
typedef __attribute__((ext_vector_type(4))) float floatx4;  // MFMA acc

// HW_REG_XCC_ID = 20 (gfx940+); encoding id | (offset<<6) | ((size-1)<<11)
#define HWREG_XCC_ID (20 | (0 << 6) | (31 << 11))

__device__ __forceinline__ unsigned short f2bf(float f) {   // RNE f32->bf16
    unsigned u = __float_as_uint(f);
    u += 0x7FFF + ((u >> 16) & 1);
    return (unsigned short)(u >> 16);
}

__device__ __forceinline__ float sigmoidf(float x) {
    return 1.f / (1.f + __expf(-x));
}

__device__ __forceinline__ float bflo(unsigned u) { return __uint_as_float(u << 16); }
__device__ __forceinline__ float bfhi(unsigned u) { return __uint_as_float(u & 0xFFFF0000u); }

// ---------------------------------------------------------------------------
// Kernel 1 (setup, fused by block range):
//   blocks 0..63      : W_lin -> bf16
//   blocks 64..113    : s_rel[r] = dot(rel_emb[r], W_attn)
//   blocks 114..309   : zero count[] AND the 8 XCD work-queue cursors
//                       (cursors live at count[N_NODES..N_NODES+7])
//   blocks 310..6559  : s_node[n] = dot(x[n], W_attn), half-wave per node
// ---------------------------------------------------------------------------
__global__ void setup_kernel(const float* __restrict__ W,
                             const float* __restrict__ x,
                             const float* __restrict__ rel,
                             const float* __restrict__ Wattn,
                             unsigned short* __restrict__ Wbf,
                             float* __restrict__ s_rel,
                             float* __restrict__ s_node,
                             int* __restrict__ count) {
    const int b = blockIdx.x;
    if (b < 64) {
        const int i = b * 256 + threadIdx.x;          // 0..16383
        Wbf[i] = f2bf(W[i]);
    } else if (b < 114) {
        const int wave = (b - 64) * 4 + (threadIdx.x >> 6);
        const int lane = threadIdx.x & 63;
        if (wave < N_REL) {
            const float* __restrict__ row = rel + (size_t)wave * D;
            float a = fmaf(row[lane], Wattn[lane],
                           row[lane + 64] * Wattn[lane + 64]);
#pragma unroll
            for (int off = 32; off; off >>= 1)
                a += __shfl_down(a, off);
            if (lane == 0) s_rel[wave] = a;
        }
    } else if (b < 310) {
        const int i = (b - 114) * 256 + threadIdx.x;
        if (i < N_NODES + RANGES) count[i] = 0;       // counts + cursors
    } else {
        const int node = (b - 310) * 8 + (threadIdx.x >> 5);
        const int sub  = threadIdx.x & 31;
        if (node < N_NODES) {
            const float4 xv = ((const float4*)(x + (size_t)node * D))[sub];
            const float4 wv = ((const float4*)Wattn)[sub];
            float a = xv.x * wv.x + xv.y * wv.y + xv.z * wv.z + xv.w * wv.w;
#pragma unroll
            for (int off = 16; off; off >>= 1)
                a += __shfl_xor(a, off);              // within 32-lane half
            if (sub == 0) s_node[node] = a;
        }
    }
}

// ---------------------------------------------------------------------------
// Kernel 2: xt = x @ W_lin.T via MFMA 16x16x32 bf16 (standalone, lean).
// One wave per 16 nodes, no LDS. Layouts per m89/m120.
// ---------------------------------------------------------------------------
__global__ void xtrans_mfma_kernel(const float* __restrict__ x,
                                   const unsigned short* __restrict__ Wbf,
                                   unsigned short* __restrict__ xt) {
    const int wid = (blockIdx.x * blockDim.x + threadIdx.x) >> 6;
    if (wid >= N_NODES / 16) return;           // 3125 waves exactly
    const int lane = threadIdx.x & 63;
    const int r16  = lane & 15;
    const int quad = lane >> 4;
    const int m0   = wid * 16;

    short8 af[4];
#pragma unroll
    for (int s = 0; s < 4; ++s) {
        const int k0 = s * 32 + quad * 8;
        const float* __restrict__ xr = x + (size_t)(m0 + r16) * D + k0;
        const float4 lo = *(const float4*)(xr);
        const float4 hi = *(const float4*)(xr + 4);
        short8 a;
        a[0] = (short)f2bf(lo.x); a[1] = (short)f2bf(lo.y);
        a[2] = (short)f2bf(lo.z); a[3] = (short)f2bf(lo.w);
        a[4] = (short)f2bf(hi.x); a[5] = (short)f2bf(hi.y);
        a[6] = (short)f2bf(hi.z); a[7] = (short)f2bf(hi.w);
        af[s] = a;
    }

#pragma unroll
    for (int t = 0; t < 8; ++t) {
        floatx4 acc = {0.f, 0.f, 0.f, 0.f};
#pragma unroll
        for (int s = 0; s < 4; ++s) {
            const int k0 = s * 32 + quad * 8;
            const short8 b = *(const short8*)(Wbf + (size_t)(t * 16 + r16) * D + k0);
            acc = __builtin_amdgcn_mfma_f32_16x16x32_bf16(af[s], b, acc, 0, 0, 0);
        }
#pragma unroll
        for (int r = 0; r < 4; ++r) {
            const int orow = m0 + quad * 4 + r;
            xt[(size_t)orow * D + t * 16 + r16] = f2bf(acc[r]);
        }
    }
}

// ---------------------------------------------------------------------------
// Kernel 3: XCD-verified partitioned bucket scatter.
// Each block reads its REAL XCD id (s_getreg HW_REG_XCC_ID) and drains that
// XCD's work queue (cursor[xcd] -> chunk ids), processing only targets in
// range [xcd*6250, (xcd+1)*6250). All bucket writes of one range then live in
// ONE XCD's L2 (1.6 MB slice << 4 MB) -> each dirty line flushes once.
// After its own queue, it steals from the other 7 queues, so every
// (chunk, range) pair is processed exactly once REGARDLESS of the true
// block->XCD mapping (wrong hwreg id degrades perf, never correctness).
// ---------------------------------------------------------------------------
__global__ void scatter_kernel(const int* __restrict__ src_idx,
                               const int* __restrict__ tgt_idx,
                               const int* __restrict__ etype,
                               const float* __restrict__ s_node,
                               const float* __restrict__ s_rel,
                               int* __restrict__ count,
                               int* __restrict__ cursor,      // 8 ints, zeroed
                               unsigned* __restrict__ sorted) {
    __shared__ int sh_chunk;
    const unsigned my_xcd =
        __builtin_amdgcn_s_getreg(HWREG_XCC_ID) & (RANGES - 1);

    for (int j = 0; j < RANGES; ++j) {
        const int q  = (my_xcd + j) & (RANGES - 1);
        const int lo = q * NODES_PER_RANGE;
        const int hi = lo + NODES_PER_RANGE;
        for (;;) {
            if (threadIdx.x == 0)
                sh_chunk = atomicAdd(&cursor[q], 1);
            __syncthreads();
            const int c = sh_chunk;
            __syncthreads();
            if (c >= N_CHUNKS) break;

            const int base = c * CHUNK_EDGES + threadIdx.x;
#pragma unroll
            for (int it = 0; it < CHUNK_EDGES / 256; ++it) {
                const int e = base + it * 256;
                const int t = tgt_idx[e];                    // coalesced
                if (t >= lo && t < hi) {
                    const int s = src_idx[e];
                    const int r = etype[e];
                    const float logit = s_node[s] + s_rel[r];
                    const unsigned rec =
                        ((unsigned)f2bf(sigmoidf(logit)) << 16) | (unsigned)s;
                    const int k = atomicAdd(&count[t], 1);
                    sorted[t * CAP + k] = rec;               // XCD-local write
                }
            }
        }
    }
}

// ---------------------------------------------------------------------------
// Kernel 4: gather + fused ReLU. FOUR nodes per wave (16 lanes each); lane
// owns 8 bf16 dims (one uint4 = 16 B -> 16 lanes x 16 B = full 256 B row in
// one instruction). Records pulled 4-at-a-time (uint4) -> 16 row loads in
// flight per wave.
// ---------------------------------------------------------------------------
__device__ __forceinline__ void gproc8(unsigned r,
                                       const unsigned short* __restrict__ xt,
                                       int sub, float* acc) {
    const unsigned src = r & 0xFFFFu;
    const float a = __uint_as_float(r & 0xFFFF0000u);
    const uint4 p = *(const uint4*)(xt + (size_t)src * D + sub * 8);
    acc[0] = fmaf(a, bflo(p.x), acc[0]);
    acc[1] = fmaf(a, bfhi(p.x), acc[1]);
    acc[2] = fmaf(a, bflo(p.y), acc[2]);
    acc[3] = fmaf(a, bfhi(p.y), acc[3]);
    acc[4] = fmaf(a, bflo(p.z), acc[4]);
    acc[5] = fmaf(a, bfhi(p.z), acc[5]);
    acc[6] = fmaf(a, bflo(p.w), acc[6]);
    acc[7] = fmaf(a, bfhi(p.w), acc[7]);
}

__global__ void gather_kernel(const int* __restrict__ count,
                              const unsigned* __restrict__ sorted,
                              const unsigned short* __restrict__ xt,
                              float* __restrict__ out) {
    const int wid  = (blockIdx.x * blockDim.x + threadIdx.x) >> 6;
    const int lane = threadIdx.x & 63;
    const int grp  = lane >> 4;          // 0..3: node within wave
    const int sub  = lane & 15;          // dim group: dims sub*8..sub*8+7
    const int t    = wid * 4 + grp;
    if (t >= N_NODES) return;

    const int cnt = count[t];
    const unsigned* __restrict__ rec = sorted + (size_t)t * CAP;

    float acc[8] = {0.f, 0.f, 0.f, 0.f, 0.f, 0.f, 0.f, 0.f};
    int i = 0;
    for (; i + 4 <= cnt; i += 4) {
        const uint4 r4 = *(const uint4*)(rec + i);   // broadcast in 16-lane grp
        gproc8(r4.x, xt, sub, acc);
        gproc8(r4.y, xt, sub, acc);
        gproc8(r4.z, xt, sub, acc);
        gproc8(r4.w, xt, sub, acc);
    }
    for (; i < cnt; ++i)
        gproc8(rec[i], xt, sub, acc);

    float4 o0, o1;
    o0.x = fmaxf(acc[0], 0.f); o0.y = fmaxf(acc[1], 0.f);
    o0.z = fmaxf(acc[2], 0.f); o0.w = fmaxf(acc[3], 0.f);
    o1.x = fmaxf(acc[4], 0.f); o1.y = fmaxf(acc[5], 0.f);
    o1.z = fmaxf(acc[6], 0.f); o1.w = fmaxf(acc[7], 0.f);
    float* orow = out + (size_t)t * D + sub * 8;
    *(float4*)(orow)     = o0;
    *(float4*)(orow + 4) = o1;
}

extern "C" void kernel_launch(void* const* d_in, const int* in_sizes, int n_in,
                              void* d_out, int out_size, void* d_ws, size_t ws_size,
                              hipStream_t stream) {
    const float* x        = (const float*)d_in[0];              // [N, 128]
    const int*   edge_idx = (const int*)d_in[1];                // [2, E]
    const int*   etype    = (const int*)d_in[2];                // [E]
    const float* rel_emb  = (const float*)d_in[3];              // [R, 128]
    const float* W_lin    = (const float*)d_in[4];              // [128, 128]
    const float* W_attn   = (const float*)d_in[5];              // [1, 128]
    float* out = (float*)d_out;                                 // [N, 128]

    const int* src_idx = edge_idx;
    const int* tgt_idx = edge_idx + N_EDGES;

    // workspace layout (~26 MB total)
    unsigned short* xt   = (unsigned short*)d_ws;               // 12.8 MB (bf16)
    float* s_node        = (float*)(xt + (size_t)N_NODES * D);  // 200 KB
    float* s_rel         = s_node + N_NODES;                    // 800 B
    unsigned short* Wbf  = (unsigned short*)(s_rel + N_REL);    // 32 KB (bf16)
    int*   count         = (int*)(Wbf + D * D);                 // 200 KB + cursors
    int*   cursor        = count + N_NODES;                     // 8 ints
    unsigned* sorted     = (unsigned*)(count + N_NODES + RANGES); // 12.8 MB

    // 1. setup: W->bf16, s_rel, zero count+cursors, s_node
    setup_kernel<<<dim3(310 + (N_NODES + 7) / 8), dim3(256), 0, stream>>>(
        W_lin, x, rel_emb, W_attn, Wbf, s_rel, s_node, count);

    // 2. xt = x @ W_lin.T (MFMA, standalone)
    xtrans_mfma_kernel<<<dim3((N_NODES / 16 * 64 + 255) / 256), dim3(256), 0, stream>>>(
        x, Wbf, xt);

    // 3. XCD-verified partitioned scatter (2000 blocks, 8 work queues)
    scatter_kernel<<<dim3(N_CHUNKS * RANGES), dim3(256), 0, stream>>>(
        src_idx, tgt_idx, etype, s_node, s_rel, count, cursor, sorted);

    // 4. gather + fused ReLU (4 nodes per wave, 16 nodes per block)
    gather_kernel<<<dim3((N_NODES + 15) / 16), dim3(256), 0, stream>>>(
        count, sorted, xt, out);
}

// Round 11
// 177.357 us; speedup vs baseline: 2.0384x; 2.0384x over previous
//
#include <hip/hip_runtime.h>
#include <hip/hip_bf16.h>

#define N_NODES 50000
#define N_EDGES 640000
#define N_REL   200
#define D       128
#define CAP     64              // bucket capacity; max degree ~35 (Poisson 12.8)

#define XT_BLOCKS   782                         // ceil(3125 waves / 4)
#define SN_BLOCKS   6250                        // 8 nodes/block
#define SR_BLOCKS   50                          // 4 waves/block -> 200 rows
#define CZ_BLOCKS   196                         // 196*256 >= 50000
#define TOTAL_B1    (XT_BLOCKS + SN_BLOCKS + SR_BLOCKS + CZ_BLOCKS)

typedef __attribute__((ext_vector_type(8))) short short8;   // 8 bf16 (4 VGPRs)
typedef __attribute__((ext_vector_type(4))) float floatx4;  // MFMA acc

__device__ __forceinline__ unsigned short f2bf(float f) {   // RNE f32->bf16
    unsigned u = __float_as_uint(f);
    u += 0x7FFF + ((u >> 16) & 1);
    return (unsigned short)(u >> 16);
}

__device__ __forceinline__ float sigmoidf(float x) {
    return 1.f / (1.f + __expf(-x));
}

__device__ __forceinline__ float bflo(unsigned u) { return __uint_as_float(u << 16); }
__device__ __forceinline__ float bfhi(unsigned u) { return __uint_as_float(u & 0xFFFF0000u); }

// ---------------------------------------------------------------------------
// Kernel 1 (fused setup + xtrans; no inter-block dependencies):
//   blocks [0, 782)        : xtrans via MFMA 16x16x32 bf16, one wave/16 nodes.
//                            W is read as fp32 and converted to bf16 INLINE
//                            (W is 64 KB, L1/L2-hot across all waves), so no
//                            separate Wbf pass is needed.
//   blocks [782, 7032)     : s_node[n] = dot(x[n], W_attn), half-wave/node
//   blocks [7032, 7082)    : s_rel[r] = dot(rel_emb[r], W_attn)
//   blocks [7082, 7278)    : zero count[]
// Heavy xtrans blocks are FIRST so they launch earliest.
// ---------------------------------------------------------------------------
__global__ void fused_setup_xtrans_kernel(const float* __restrict__ x,
                                          const float* __restrict__ W,
                                          const float* __restrict__ rel,
                                          const float* __restrict__ Wattn,
                                          unsigned short* __restrict__ xt,
                                          float* __restrict__ s_node,
                                          float* __restrict__ s_rel,
                                          int* __restrict__ count) {
    const int b = blockIdx.x;
    if (b < XT_BLOCKS) {
        // ---------------- xtrans (MFMA), layouts per m89/m120 --------------
        const int wid = b * 4 + (threadIdx.x >> 6);
        if (wid >= N_NODES / 16) return;       // 3125 waves
        const int lane = threadIdx.x & 63;
        const int r16  = lane & 15;
        const int quad = lane >> 4;
        const int m0   = wid * 16;

        short8 af[4];
#pragma unroll
        for (int s = 0; s < 4; ++s) {
            const int k0 = s * 32 + quad * 8;
            const float* __restrict__ xr = x + (size_t)(m0 + r16) * D + k0;
            const float4 lo = *(const float4*)(xr);
            const float4 hi = *(const float4*)(xr + 4);
            short8 a;
            a[0] = (short)f2bf(lo.x); a[1] = (short)f2bf(lo.y);
            a[2] = (short)f2bf(lo.z); a[3] = (short)f2bf(lo.w);
            a[4] = (short)f2bf(hi.x); a[5] = (short)f2bf(hi.y);
            a[6] = (short)f2bf(hi.z); a[7] = (short)f2bf(hi.w);
            af[s] = a;
        }

#pragma unroll
        for (int t = 0; t < 8; ++t) {
            floatx4 acc = {0.f, 0.f, 0.f, 0.f};
#pragma unroll
            for (int s = 0; s < 4; ++s) {
                const int k0 = s * 32 + quad * 8;
                // inline fp32 W load + bf16 convert (B^T row = W row)
                const float* __restrict__ wr =
                    W + (size_t)(t * 16 + r16) * D + k0;
                const float4 wlo = *(const float4*)(wr);
                const float4 whi = *(const float4*)(wr + 4);
                short8 bb;
                bb[0] = (short)f2bf(wlo.x); bb[1] = (short)f2bf(wlo.y);
                bb[2] = (short)f2bf(wlo.z); bb[3] = (short)f2bf(wlo.w);
                bb[4] = (short)f2bf(whi.x); bb[5] = (short)f2bf(whi.y);
                bb[6] = (short)f2bf(whi.z); bb[7] = (short)f2bf(whi.w);
                acc = __builtin_amdgcn_mfma_f32_16x16x32_bf16(af[s], bb, acc, 0, 0, 0);
            }
#pragma unroll
            for (int r = 0; r < 4; ++r) {
                const int orow = m0 + quad * 4 + r;
                xt[(size_t)orow * D + t * 16 + r16] = f2bf(acc[r]);
            }
        }
    } else if (b < XT_BLOCKS + SN_BLOCKS) {
        // ---------------- s_node -------------------------------------------
        const int node = (b - XT_BLOCKS) * 8 + (threadIdx.x >> 5);
        const int sub  = threadIdx.x & 31;
        if (node < N_NODES) {
            const float4 xv = ((const float4*)(x + (size_t)node * D))[sub];
            const float4 wv = ((const float4*)Wattn)[sub];
            float a = xv.x * wv.x + xv.y * wv.y + xv.z * wv.z + xv.w * wv.w;
#pragma unroll
            for (int off = 16; off; off >>= 1)
                a += __shfl_xor(a, off);              // within 32-lane half
            if (sub == 0) s_node[node] = a;
        }
    } else if (b < XT_BLOCKS + SN_BLOCKS + SR_BLOCKS) {
        // ---------------- s_rel --------------------------------------------
        const int wave = (b - XT_BLOCKS - SN_BLOCKS) * 4 + (threadIdx.x >> 6);
        const int lane = threadIdx.x & 63;
        if (wave < N_REL) {
            const float* __restrict__ row = rel + (size_t)wave * D;
            float a = fmaf(row[lane], Wattn[lane],
                           row[lane + 64] * Wattn[lane + 64]);
#pragma unroll
            for (int off = 32; off; off >>= 1)
                a += __shfl_down(a, off);
            if (lane == 0) s_rel[wave] = a;
        }
    } else {
        // ---------------- zero count ---------------------------------------
        const int i = (b - XT_BLOCKS - SN_BLOCKS - SR_BLOCKS) * 256 + threadIdx.x;
        if (i < N_NODES) count[i] = 0;
    }
}

// ---------------------------------------------------------------------------
// Kernel 2: fused hist + scatter into fixed-capacity buckets (round-7 exact:
// 1 edge/thread, max TLP). Record value computed BEFORE the atomic so only
// the store address depends on the atomic result.
// Record = 4 B: {attn_bf16:16 | src:16} at sorted[t*CAP + k].
// Known cost ~45-48 us; bound by same-line atomic serialization at L2
// (R6/R7/R8/R10 evidence) — partitioning/queueing tested and rejected.
// ---------------------------------------------------------------------------
__global__ void bucket_scatter_kernel(const int* __restrict__ src_idx,
                                      const int* __restrict__ tgt_idx,
                                      const int* __restrict__ etype,
                                      const float* __restrict__ s_node,
                                      const float* __restrict__ s_rel,
                                      int* __restrict__ count,
                                      unsigned* __restrict__ sorted) {
    const int e = blockIdx.x * 256 + threadIdx.x;
    if (e >= N_EDGES) return;
    const int s = src_idx[e];
    const int t = tgt_idx[e];
    const int r = etype[e];

    const float logit = s_node[s] + s_rel[r];
    const unsigned rec = ((unsigned)f2bf(sigmoidf(logit)) << 16) | (unsigned)s;

    const int k = atomicAdd(&count[t], 1);
    sorted[t * CAP + k] = rec;
}

// ---------------------------------------------------------------------------
// Kernel 3: gather + fused ReLU. FOUR nodes per wave (16 lanes each); lane
// owns 8 bf16 dims (uint4 = 16 B -> 16 lanes x 16 B = full 256 B row per
// instruction). Records pulled 4-at-a-time (uint4) -> 16 row loads in
// flight per wave. (Round-10 version, correctness-verified.)
// ---------------------------------------------------------------------------
__device__ __forceinline__ void gproc8(unsigned r,
                                       const unsigned short* __restrict__ xt,
                                       int sub, float* acc) {
    const unsigned src = r & 0xFFFFu;
    const float a = __uint_as_float(r & 0xFFFF0000u);
    const uint4 p = *(const uint4*)(xt + (size_t)src * D + sub * 8);
    acc[0] = fmaf(a, bflo(p.x), acc[0]);
    acc[1] = fmaf(a, bfhi(p.x), acc[1]);
    acc[2] = fmaf(a, bflo(p.y), acc[2]);
    acc[3] = fmaf(a, bfhi(p.y), acc[3]);
    acc[4] = fmaf(a, bflo(p.z), acc[4]);
    acc[5] = fmaf(a, bfhi(p.z), acc[5]);
    acc[6] = fmaf(a, bflo(p.w), acc[6]);
    acc[7] = fmaf(a, bfhi(p.w), acc[7]);
}

__global__ void gather_kernel(const int* __restrict__ count,
                              const unsigned* __restrict__ sorted,
                              const unsigned short* __restrict__ xt,
                              float* __restrict__ out) {
    const int wid  = (blockIdx.x * blockDim.x + threadIdx.x) >> 6;
    const int lane = threadIdx.x & 63;
    const int grp  = lane >> 4;          // 0..3: node within wave
    const int sub  = lane & 15;          // dim group: dims sub*8..sub*8+7
    const int t    = wid * 4 + grp;
    if (t >= N_NODES) return;

    const int cnt = count[t];
    const unsigned* __restrict__ rec = sorted + (size_t)t * CAP;

    float acc[8] = {0.f, 0.f, 0.f, 0.f, 0.f, 0.f, 0.f, 0.f};
    int i = 0;
    for (; i + 4 <= cnt; i += 4) {
        const uint4 r4 = *(const uint4*)(rec + i);   // broadcast in 16-lane grp
        gproc8(r4.x, xt, sub, acc);
        gproc8(r4.y, xt, sub, acc);
        gproc8(r4.z, xt, sub, acc);
        gproc8(r4.w, xt, sub, acc);
    }
    for (; i < cnt; ++i)
        gproc8(rec[i], xt, sub, acc);

    float4 o0, o1;
    o0.x = fmaxf(acc[0], 0.f); o0.y = fmaxf(acc[1], 0.f);
    o0.z = fmaxf(acc[2], 0.f); o0.w = fmaxf(acc[3], 0.f);
    o1.x = fmaxf(acc[4], 0.f); o1.y = fmaxf(acc[5], 0.f);
    o1.z = fmaxf(acc[6], 0.f); o1.w = fmaxf(acc[7], 0.f);
    float* orow = out + (size_t)t * D + sub * 8;
    *(float4*)(orow)     = o0;
    *(float4*)(orow + 4) = o1;
}

extern "C" void kernel_launch(void* const* d_in, const int* in_sizes, int n_in,
                              void* d_out, int out_size, void* d_ws, size_t ws_size,
                              hipStream_t stream) {
    const float* x        = (const float*)d_in[0];              // [N, 128]
    const int*   edge_idx = (const int*)d_in[1];                // [2, E]
    const int*   etype    = (const int*)d_in[2];                // [E]
    const float* rel_emb  = (const float*)d_in[3];              // [R, 128]
    const float* W_lin    = (const float*)d_in[4];              // [128, 128]
    const float* W_attn   = (const float*)d_in[5];              // [1, 128]
    float* out = (float*)d_out;                                 // [N, 128]

    const int* src_idx = edge_idx;
    const int* tgt_idx = edge_idx + N_EDGES;

    // workspace layout (~26 MB total)
    unsigned short* xt   = (unsigned short*)d_ws;               // 12.8 MB (bf16)
    float* s_node        = (float*)(xt + (size_t)N_NODES * D);  // 200 KB
    float* s_rel         = s_node + N_NODES;                    // 800 B
    int*   count         = (int*)(s_rel + N_REL);               // 200 KB
    unsigned* sorted     = (unsigned*)(count + N_NODES);        // 12.8 MB

    // 1. fused setup + xtrans (7278 blocks; xtrans first)
    fused_setup_xtrans_kernel<<<dim3(TOTAL_B1), dim3(256), 0, stream>>>(
        x, W_lin, rel_emb, W_attn, xt, s_node, s_rel, count);

    // 2. bucket scatter, 1 edge/thread
    bucket_scatter_kernel<<<dim3((N_EDGES + 255) / 256), dim3(256), 0, stream>>>(
        src_idx, tgt_idx, etype, s_node, s_rel, count, sorted);

    // 3. gather + fused ReLU (4 nodes/wave, 16 nodes/block)
    gather_kernel<<<dim3((N_NODES + 15) / 16), dim3(256), 0, stream>>>(
        count, sorted, xt, out);
}

// Round 12
// 172.113 us; speedup vs baseline: 2.1005x; 1.0305x over previous
//
#include <hip/hip_runtime.h>
#include <hip/hip_bf16.h>

#define N_NODES 50000
#define N_EDGES 640000
#define N_REL   200
#define D       128
#define CAP     64              // bucket capacity; max degree ~35 (Poisson 12.8)

typedef __attribute__((ext_vector_type(8))) short short8;   // 8 bf16 (4 VGPRs)
typedef __attribute__((ext_vector_type(4))) float floatx4;  // MFMA acc

__device__ __forceinline__ unsigned short f2bf(float f) {   // RNE f32->bf16
    unsigned u = __float_as_uint(f);
    u += 0x7FFF + ((u >> 16) & 1);
    return (unsigned short)(u >> 16);
}

__device__ __forceinline__ float sigmoidf(float x) {
    return 1.f / (1.f + __expf(-x));
}

__device__ __forceinline__ float bflo(unsigned u) { return __uint_as_float(u << 16); }
__device__ __forceinline__ float bfhi(unsigned u) { return __uint_as_float(u & 0xFFFF0000u); }

// ---------------------------------------------------------------------------
// Kernel 1 (setup, fused by block range — R9 version, known-good):
//   blocks 0..63      : W_lin -> bf16 (one pass; xtrans reads Wbf)
//   blocks 64..113    : s_rel[r] = dot(rel_emb[r], W_attn)
//   blocks 114..309   : zero count[]
//   blocks 310..6559  : s_node[n] = dot(x[n], W_attn), half-wave per node
// ---------------------------------------------------------------------------
__global__ void setup_kernel(const float* __restrict__ W,
                             const float* __restrict__ x,
                             const float* __restrict__ rel,
                             const float* __restrict__ Wattn,
                             unsigned short* __restrict__ Wbf,
                             float* __restrict__ s_rel,
                             float* __restrict__ s_node,
                             int* __restrict__ count) {
    const int b = blockIdx.x;
    if (b < 64) {
        const int i = b * 256 + threadIdx.x;          // 0..16383
        Wbf[i] = f2bf(W[i]);
    } else if (b < 114) {
        const int wave = (b - 64) * 4 + (threadIdx.x >> 6);
        const int lane = threadIdx.x & 63;
        if (wave < N_REL) {
            const float* __restrict__ row = rel + (size_t)wave * D;
            float a = fmaf(row[lane], Wattn[lane],
                           row[lane + 64] * Wattn[lane + 64]);
#pragma unroll
            for (int off = 32; off; off >>= 1)
                a += __shfl_down(a, off);
            if (lane == 0) s_rel[wave] = a;
        }
    } else if (b < 310) {
        const int i = (b - 114) * 256 + threadIdx.x;
        if (i < N_NODES) count[i] = 0;
    } else {
        const int node = (b - 310) * 8 + (threadIdx.x >> 5);
        const int sub  = threadIdx.x & 31;
        if (node < N_NODES) {
            const float4 xv = ((const float4*)(x + (size_t)node * D))[sub];
            const float4 wv = ((const float4*)Wattn)[sub];
            float a = xv.x * wv.x + xv.y * wv.y + xv.z * wv.z + xv.w * wv.w;
#pragma unroll
            for (int off = 16; off; off >>= 1)
                a += __shfl_xor(a, off);              // within 32-lane half
            if (sub == 0) s_node[node] = a;
        }
    }
}

// ---------------------------------------------------------------------------
// Kernel 2: xt = x @ W_lin.T via MFMA 16x16x32 bf16 (standalone, lean —
// R9 version, known-good). One wave per 16 nodes, no LDS. Layouts m89/m120.
// ---------------------------------------------------------------------------
__global__ void xtrans_mfma_kernel(const float* __restrict__ x,
                                   const unsigned short* __restrict__ Wbf,
                                   unsigned short* __restrict__ xt) {
    const int wid = (blockIdx.x * blockDim.x + threadIdx.x) >> 6;
    if (wid >= N_NODES / 16) return;           // 3125 waves exactly
    const int lane = threadIdx.x & 63;
    const int r16  = lane & 15;
    const int quad = lane >> 4;
    const int m0   = wid * 16;

    short8 af[4];
#pragma unroll
    for (int s = 0; s < 4; ++s) {
        const int k0 = s * 32 + quad * 8;
        const float* __restrict__ xr = x + (size_t)(m0 + r16) * D + k0;
        const float4 lo = *(const float4*)(xr);
        const float4 hi = *(const float4*)(xr + 4);
        short8 a;
        a[0] = (short)f2bf(lo.x); a[1] = (short)f2bf(lo.y);
        a[2] = (short)f2bf(lo.z); a[3] = (short)f2bf(lo.w);
        a[4] = (short)f2bf(hi.x); a[5] = (short)f2bf(hi.y);
        a[6] = (short)f2bf(hi.z); a[7] = (short)f2bf(hi.w);
        af[s] = a;
    }

#pragma unroll
    for (int t = 0; t < 8; ++t) {
        floatx4 acc = {0.f, 0.f, 0.f, 0.f};
#pragma unroll
        for (int s = 0; s < 4; ++s) {
            const int k0 = s * 32 + quad * 8;
            const short8 b = *(const short8*)(Wbf + (size_t)(t * 16 + r16) * D + k0);
            acc = __builtin_amdgcn_mfma_f32_16x16x32_bf16(af[s], b, acc, 0, 0, 0);
        }
#pragma unroll
        for (int r = 0; r < 4; ++r) {
            const int orow = m0 + quad * 4 + r;
            xt[(size_t)orow * D + t * 16 + r16] = f2bf(acc[r]);
        }
    }
}

// ---------------------------------------------------------------------------
// Kernel 3: bucket scatter, 1 edge/thread (R7 structure) + NONTEMPORAL record
// store. Discriminating test: if scatter's ~47 us is per-XCD L2 write-amp
// (same 64 B line dirtied in up to 8 non-coherent L2s -> 38.5 MB writeback),
// nt stores route past L2 and sectors combine once -> WRITE_SIZE ~<12 MB and
// time drops. If unchanged, the bound is same-address atomic serialization.
// ---------------------------------------------------------------------------
__global__ void bucket_scatter_kernel(const int* __restrict__ src_idx,
                                      const int* __restrict__ tgt_idx,
                                      const int* __restrict__ etype,
                                      const float* __restrict__ s_node,
                                      const float* __restrict__ s_rel,
                                      int* __restrict__ count,
                                      unsigned* __restrict__ sorted) {
    const int e = blockIdx.x * 256 + threadIdx.x;
    if (e >= N_EDGES) return;
    const int s = src_idx[e];
    const int t = tgt_idx[e];
    const int r = etype[e];

    const float logit = s_node[s] + s_rel[r];
    const unsigned rec = ((unsigned)f2bf(sigmoidf(logit)) << 16) | (unsigned)s;

    const int k = atomicAdd(&count[t], 1);
    __builtin_nontemporal_store(rec, &sorted[t * CAP + k]);
}

// ---------------------------------------------------------------------------
// Kernel 4: gather + fused ReLU (R10 version, verified). FOUR nodes per wave
// (16 lanes each); lane owns 8 bf16 dims (uint4 -> full 256 B row per
// instruction). Records pulled 4-at-a-time -> 16 row loads in flight/wave.
// ---------------------------------------------------------------------------
__device__ __forceinline__ void gproc8(unsigned r,
                                       const unsigned short* __restrict__ xt,
                                       int sub, float* acc) {
    const unsigned src = r & 0xFFFFu;
    const float a = __uint_as_float(r & 0xFFFF0000u);
    const uint4 p = *(const uint4*)(xt + (size_t)src * D + sub * 8);
    acc[0] = fmaf(a, bflo(p.x), acc[0]);
    acc[1] = fmaf(a, bfhi(p.x), acc[1]);
    acc[2] = fmaf(a, bflo(p.y), acc[2]);
    acc[3] = fmaf(a, bfhi(p.y), acc[3]);
    acc[4] = fmaf(a, bflo(p.z), acc[4]);
    acc[5] = fmaf(a, bfhi(p.z), acc[5]);
    acc[6] = fmaf(a, bflo(p.w), acc[6]);
    acc[7] = fmaf(a, bfhi(p.w), acc[7]);
}

__global__ void gather_kernel(const int* __restrict__ count,
                              const unsigned* __restrict__ sorted,
                              const unsigned short* __restrict__ xt,
                              float* __restrict__ out) {
    const int wid  = (blockIdx.x * blockDim.x + threadIdx.x) >> 6;
    const int lane = threadIdx.x & 63;
    const int grp  = lane >> 4;          // 0..3: node within wave
    const int sub  = lane & 15;          // dim group: dims sub*8..sub*8+7
    const int t    = wid * 4 + grp;
    if (t >= N_NODES) return;

    const int cnt = count[t];
    const unsigned* __restrict__ rec = sorted + (size_t)t * CAP;

    float acc[8] = {0.f, 0.f, 0.f, 0.f, 0.f, 0.f, 0.f, 0.f};
    int i = 0;
    for (; i + 4 <= cnt; i += 4) {
        const uint4 r4 = *(const uint4*)(rec + i);   // broadcast in 16-lane grp
        gproc8(r4.x, xt, sub, acc);
        gproc8(r4.y, xt, sub, acc);
        gproc8(r4.z, xt, sub, acc);
        gproc8(r4.w, xt, sub, acc);
    }
    for (; i < cnt; ++i)
        gproc8(rec[i], xt, sub, acc);

    float4 o0, o1;
    o0.x = fmaxf(acc[0], 0.f); o0.y = fmaxf(acc[1], 0.f);
    o0.z = fmaxf(acc[2], 0.f); o0.w = fmaxf(acc[3], 0.f);
    o1.x = fmaxf(acc[4], 0.f); o1.y = fmaxf(acc[5], 0.f);
    o1.z = fmaxf(acc[6], 0.f); o1.w = fmaxf(acc[7], 0.f);
    float* orow = out + (size_t)t * D + sub * 8;
    *(float4*)(orow)     = o0;
    *(float4*)(orow + 4) = o1;
}

extern "C" void kernel_launch(void* const* d_in, const int* in_sizes, int n_in,
                              void* d_out, int out_size, void* d_ws, size_t ws_size,
                              hipStream_t stream) {
    const float* x        = (const float*)d_in[0];              // [N, 128]
    const int*   edge_idx = (const int*)d_in[1];                // [2, E]
    const int*   etype    = (const int*)d_in[2];                // [E]
    const float* rel_emb  = (const float*)d_in[3];              // [R, 128]
    const float* W_lin    = (const float*)d_in[4];              // [128, 128]
    const float* W_attn   = (const float*)d_in[5];              // [1, 128]
    float* out = (float*)d_out;                                 // [N, 128]

    const int* src_idx = edge_idx;
    const int* tgt_idx = edge_idx + N_EDGES;

    // workspace layout (~26 MB total)
    unsigned short* xt   = (unsigned short*)d_ws;               // 12.8 MB (bf16)
    float* s_node        = (float*)(xt + (size_t)N_NODES * D);  // 200 KB
    float* s_rel         = s_node + N_NODES;                    // 800 B
    unsigned short* Wbf  = (unsigned short*)(s_rel + N_REL);    // 32 KB (bf16)
    int*   count         = (int*)(Wbf + D * D);                 // 200 KB
    unsigned* sorted     = (unsigned*)(count + N_NODES);        // 12.8 MB

    // 1. setup: W->bf16, s_rel, zero count, s_node
    setup_kernel<<<dim3(310 + (N_NODES + 7) / 8), dim3(256), 0, stream>>>(
        W_lin, x, rel_emb, W_attn, Wbf, s_rel, s_node, count);

    // 2. xt = x @ W_lin.T (MFMA, standalone, Wbf-based)
    xtrans_mfma_kernel<<<dim3((N_NODES / 16 * 64 + 255) / 256), dim3(256), 0, stream>>>(
        x, Wbf, xt);

    // 3. bucket scatter, 1 edge/thread, nontemporal record store
    bucket_scatter_kernel<<<dim3((N_EDGES + 255) / 256), dim3(256), 0, stream>>>(
        src_idx, tgt_idx, etype, s_node, s_rel, count, sorted);

    // 4. gather + fused ReLU (4 nodes/wave, 16 nodes/block)
    gather_kernel<<<dim3((N_NODES + 15) / 16), dim3(256), 0, stream>>>(
        count, sorted, xt, out);
}

// Round 13
// 171.341 us; speedup vs baseline: 2.1099x; 1.0045x over previous
//
#include <hip/hip_runtime.h>
#include <hip/hip_bf16.h>

#define N_NODES 50000
#define N_EDGES 640000
#define N_REL   200
#define D       128
#define CAP     64              // bucket capacity; max degree ~35 (Poisson 12.8)
#define CSTRIDE 16              // count padded: 1 counter per 64 B L2 line

typedef __attribute__((ext_vector_type(8))) short short8;   // 8 bf16 (4 VGPRs)
typedef __attribute__((ext_vector_type(4))) float floatx4;  // MFMA acc

__device__ __forceinline__ unsigned short f2bf(float f) {   // RNE f32->bf16
    unsigned u = __float_as_uint(f);
    u += 0x7FFF + ((u >> 16) & 1);
    return (unsigned short)(u >> 16);
}

__device__ __forceinline__ float sigmoidf(float x) {
    return 1.f / (1.f + __expf(-x));
}

__device__ __forceinline__ float bflo(unsigned u) { return __uint_as_float(u << 16); }
__device__ __forceinline__ float bfhi(unsigned u) { return __uint_as_float(u & 0xFFFF0000u); }

#define ZB ((N_NODES * CSTRIDE + 255) / 256)   // 3125 zero-blocks

// ---------------------------------------------------------------------------
// Kernel 1 (setup, fused by block range):
//   blocks 0..63              : W_lin -> bf16
//   blocks 64..113            : s_rel[r] = dot(rel_emb[r], W_attn)
//   blocks 114..114+ZB-1      : zero padded count[] (3.2 MB)
//   blocks 114+ZB..+6250      : s_node[n] = dot(x[n], W_attn), half-wave/node
// ---------------------------------------------------------------------------
__global__ void setup_kernel(const float* __restrict__ W,
                             const float* __restrict__ x,
                             const float* __restrict__ rel,
                             const float* __restrict__ Wattn,
                             unsigned short* __restrict__ Wbf,
                             float* __restrict__ s_rel,
                             float* __restrict__ s_node,
                             int* __restrict__ count) {
    const int b = blockIdx.x;
    if (b < 64) {
        const int i = b * 256 + threadIdx.x;          // 0..16383
        Wbf[i] = f2bf(W[i]);
    } else if (b < 114) {
        const int wave = (b - 64) * 4 + (threadIdx.x >> 6);
        const int lane = threadIdx.x & 63;
        if (wave < N_REL) {
            const float* __restrict__ row = rel + (size_t)wave * D;
            float a = fmaf(row[lane], Wattn[lane],
                           row[lane + 64] * Wattn[lane + 64]);
#pragma unroll
            for (int off = 32; off; off >>= 1)
                a += __shfl_down(a, off);
            if (lane == 0) s_rel[wave] = a;
        }
    } else if (b < 114 + ZB) {
        const int i = (b - 114) * 256 + threadIdx.x;
        if (i < N_NODES * CSTRIDE) count[i] = 0;
    } else {
        const int node = (b - 114 - ZB) * 8 + (threadIdx.x >> 5);
        const int sub  = threadIdx.x & 31;
        if (node < N_NODES) {
            const float4 xv = ((const float4*)(x + (size_t)node * D))[sub];
            const float4 wv = ((const float4*)Wattn)[sub];
            float a = xv.x * wv.x + xv.y * wv.y + xv.z * wv.z + xv.w * wv.w;
#pragma unroll
            for (int off = 16; off; off >>= 1)
                a += __shfl_xor(a, off);              // within 32-lane half
            if (sub == 0) s_node[node] = a;
        }
    }
}

// ---------------------------------------------------------------------------
// Kernel 2: xt = x @ W_lin.T via MFMA 16x16x32 bf16 (standalone, lean,
// known-good). One wave per 16 nodes, no LDS. Layouts m89/m120.
// ---------------------------------------------------------------------------
__global__ void xtrans_mfma_kernel(const float* __restrict__ x,
                                   const unsigned short* __restrict__ Wbf,
                                   unsigned short* __restrict__ xt) {
    const int wid = (blockIdx.x * blockDim.x + threadIdx.x) >> 6;
    if (wid >= N_NODES / 16) return;           // 3125 waves exactly
    const int lane = threadIdx.x & 63;
    const int r16  = lane & 15;
    const int quad = lane >> 4;
    const int m0   = wid * 16;

    short8 af[4];
#pragma unroll
    for (int s = 0; s < 4; ++s) {
        const int k0 = s * 32 + quad * 8;
        const float* __restrict__ xr = x + (size_t)(m0 + r16) * D + k0;
        const float4 lo = *(const float4*)(xr);
        const float4 hi = *(const float4*)(xr + 4);
        short8 a;
        a[0] = (short)f2bf(lo.x); a[1] = (short)f2bf(lo.y);
        a[2] = (short)f2bf(lo.z); a[3] = (short)f2bf(lo.w);
        a[4] = (short)f2bf(hi.x); a[5] = (short)f2bf(hi.y);
        a[6] = (short)f2bf(hi.z); a[7] = (short)f2bf(hi.w);
        af[s] = a;
    }

#pragma unroll
    for (int t = 0; t < 8; ++t) {
        floatx4 acc = {0.f, 0.f, 0.f, 0.f};
#pragma unroll
        for (int s = 0; s < 4; ++s) {
            const int k0 = s * 32 + quad * 8;
            const short8 b = *(const short8*)(Wbf + (size_t)(t * 16 + r16) * D + k0);
            acc = __builtin_amdgcn_mfma_f32_16x16x32_bf16(af[s], b, acc, 0, 0, 0);
        }
#pragma unroll
        for (int r = 0; r < 4; ++r) {
            const int orow = m0 + quad * 4 + r;
            xt[(size_t)orow * D + t * 16 + r16] = f2bf(acc[r]);
        }
    }
}

// ---------------------------------------------------------------------------
// Kernel 3: bucket scatter, 1 edge/thread, PADDED counters (1 per 64 B line).
// R12's nt-store test exonerated the write path; the 47 us was atomic
// contention. With 16 counters/line, each L2 line absorbed ~205 serialized
// RMWs; padding cuts that to 12.8 -> back toward the 76 G atomics/s
// low-contention regime (R1 measurement).
// ---------------------------------------------------------------------------
__global__ void bucket_scatter_kernel(const int* __restrict__ src_idx,
                                      const int* __restrict__ tgt_idx,
                                      const int* __restrict__ etype,
                                      const float* __restrict__ s_node,
                                      const float* __restrict__ s_rel,
                                      int* __restrict__ count,
                                      unsigned* __restrict__ sorted) {
    const int e = blockIdx.x * 256 + threadIdx.x;
    if (e >= N_EDGES) return;
    const int s = src_idx[e];
    const int t = tgt_idx[e];
    const int r = etype[e];

    const float logit = s_node[s] + s_rel[r];
    const unsigned rec = ((unsigned)f2bf(sigmoidf(logit)) << 16) | (unsigned)s;

    const int k = atomicAdd(&count[t * CSTRIDE], 1);
    sorted[t * CAP + k] = rec;
}

// ---------------------------------------------------------------------------
// Kernel 4: gather + fused ReLU (verified). FOUR nodes per wave (16 lanes
// each); lane owns 8 bf16 dims (uint4 -> full 256 B row per instruction).
// Records pulled 4-at-a-time -> 16 row loads in flight/wave.
// ---------------------------------------------------------------------------
__device__ __forceinline__ void gproc8(unsigned r,
                                       const unsigned short* __restrict__ xt,
                                       int sub, float* acc) {
    const unsigned src = r & 0xFFFFu;
    const float a = __uint_as_float(r & 0xFFFF0000u);
    const uint4 p = *(const uint4*)(xt + (size_t)src * D + sub * 8);
    acc[0] = fmaf(a, bflo(p.x), acc[0]);
    acc[1] = fmaf(a, bfhi(p.x), acc[1]);
    acc[2] = fmaf(a, bflo(p.y), acc[2]);
    acc[3] = fmaf(a, bfhi(p.y), acc[3]);
    acc[4] = fmaf(a, bflo(p.z), acc[4]);
    acc[5] = fmaf(a, bfhi(p.z), acc[5]);
    acc[6] = fmaf(a, bflo(p.w), acc[6]);
    acc[7] = fmaf(a, bfhi(p.w), acc[7]);
}

__global__ void gather_kernel(const int* __restrict__ count,
                              const unsigned* __restrict__ sorted,
                              const unsigned short* __restrict__ xt,
                              float* __restrict__ out) {
    const int wid  = (blockIdx.x * blockDim.x + threadIdx.x) >> 6;
    const int lane = threadIdx.x & 63;
    const int grp  = lane >> 4;          // 0..3: node within wave
    const int sub  = lane & 15;          // dim group: dims sub*8..sub*8+7
    const int t    = wid * 4 + grp;
    if (t >= N_NODES) return;

    const int cnt = count[t * CSTRIDE];
    const unsigned* __restrict__ rec = sorted + (size_t)t * CAP;

    float acc[8] = {0.f, 0.f, 0.f, 0.f, 0.f, 0.f, 0.f, 0.f};
    int i = 0;
    for (; i + 4 <= cnt; i += 4) {
        const uint4 r4 = *(const uint4*)(rec + i);   // broadcast in 16-lane grp
        gproc8(r4.x, xt, sub, acc);
        gproc8(r4.y, xt, sub, acc);
        gproc8(r4.z, xt, sub, acc);
        gproc8(r4.w, xt, sub, acc);
    }
    for (; i < cnt; ++i)
        gproc8(rec[i], xt, sub, acc);

    float4 o0, o1;
    o0.x = fmaxf(acc[0], 0.f); o0.y = fmaxf(acc[1], 0.f);
    o0.z = fmaxf(acc[2], 0.f); o0.w = fmaxf(acc[3], 0.f);
    o1.x = fmaxf(acc[4], 0.f); o1.y = fmaxf(acc[5], 0.f);
    o1.z = fmaxf(acc[6], 0.f); o1.w = fmaxf(acc[7], 0.f);
    float* orow = out + (size_t)t * D + sub * 8;
    *(float4*)(orow)     = o0;
    *(float4*)(orow + 4) = o1;
}

extern "C" void kernel_launch(void* const* d_in, const int* in_sizes, int n_in,
                              void* d_out, int out_size, void* d_ws, size_t ws_size,
                              hipStream_t stream) {
    const float* x        = (const float*)d_in[0];              // [N, 128]
    const int*   edge_idx = (const int*)d_in[1];                // [2, E]
    const int*   etype    = (const int*)d_in[2];                // [E]
    const float* rel_emb  = (const float*)d_in[3];              // [R, 128]
    const float* W_lin    = (const float*)d_in[4];              // [128, 128]
    const float* W_attn   = (const float*)d_in[5];              // [1, 128]
    float* out = (float*)d_out;                                 // [N, 128]

    const int* src_idx = edge_idx;
    const int* tgt_idx = edge_idx + N_EDGES;

    // workspace layout (~29 MB total)
    unsigned short* xt   = (unsigned short*)d_ws;               // 12.8 MB (bf16)
    float* s_node        = (float*)(xt + (size_t)N_NODES * D);  // 200 KB
    float* s_rel         = s_node + N_NODES;                    // 800 B
    unsigned short* Wbf  = (unsigned short*)(s_rel + N_REL);    // 32 KB (bf16)
    int*   count         = (int*)(Wbf + D * D);                 // 3.2 MB (padded)
    unsigned* sorted     = (unsigned*)(count + N_NODES * CSTRIDE); // 12.8 MB

    // 1. setup: W->bf16, s_rel, zero padded count, s_node
    setup_kernel<<<dim3(114 + ZB + (N_NODES + 7) / 8), dim3(256), 0, stream>>>(
        W_lin, x, rel_emb, W_attn, Wbf, s_rel, s_node, count);

    // 2. xt = x @ W_lin.T (MFMA, standalone, Wbf-based)
    xtrans_mfma_kernel<<<dim3((N_NODES / 16 * 64 + 255) / 256), dim3(256), 0, stream>>>(
        x, Wbf, xt);

    // 3. bucket scatter, 1 edge/thread, padded counters
    bucket_scatter_kernel<<<dim3((N_EDGES + 255) / 256), dim3(256), 0, stream>>>(
        src_idx, tgt_idx, etype, s_node, s_rel, count, sorted);

    // 4. gather + fused ReLU (4 nodes/wave, 16 nodes/block)
    gather_kernel<<<dim3((N_NODES + 15) / 16), dim3(256), 0, stream>>>(
        count, sorted, xt, out);
}